// Round 7
// baseline (184.124 us; speedup 1.0000x reference)
//
#include <hip/hip_runtime.h>

#define TPB 256
#define NBLK 2048
#define NW (NBLK * TPB / 64)   // 8192 waves

template <int CTRL>
__device__ __forceinline__ float dpp_add(float v) {
    int x = __builtin_amdgcn_update_dpp(0, __float_as_int(v), CTRL, 0xf, 0xf, true);
    return v + __int_as_float(x);
}

__device__ __forceinline__ float reduce16(float s) {
    s = dpp_add<0xB1>(s);    // quad_perm xor1
    s = dpp_add<0x4E>(s);    // quad_perm xor2
    s = dpp_add<0x124>(s);   // row_ror:4
    s = dpp_add<0x128>(s);   // row_ror:8
    return s;
}

__device__ __forceinline__ float masked_val(float4 v, int idx, int b4, int c) {
    float ms = (b4     >= idx ? v.x : 0.f)
             + (b4 + 1 >= idx ? v.y : 0.f)
             + (b4 + 2 >= idx ? v.z : 0.f)
             + (b4 + 3 >= idx ? v.w : 0.f);
    return idx ? ms : ((c == 0) ? v.x : 0.f);
}

__device__ __forceinline__ float nll_term(float s, int i, const float* __restrict__ w) {
    return -__logf(fminf(fmaxf(s, 1e-15f), 1.0f)) * w[i];
}

__global__ __launch_bounds__(TPB, 8) void CLL_main(
    const float* __restrict__ y_pred,
    const int*   __restrict__ y_true,
    const float* __restrict__ w,
    double*      __restrict__ acc,
    int*         __restrict__ ticket,
    float*       __restrict__ out,
    const int B)
{
    const int lane = threadIdx.x & 63;
    const int wv   = threadIdx.x >> 6;   // wave within block
    const int c    = lane & 15;          // chunk within row (4 floats)
    const int sub  = lane >> 4;          // row within quad
    const int b4   = c << 2;
    const int wid  = (blockIdx.x * TPB + threadIdx.x) >> 6;
    const int nquads = (B + 3) >> 2;
    const int F = B / (NW * 32);         // full 32-row iterations per wave (8 for B=2^21)

    float local = 0.0f;

    if (F > 0) {
        // idx vector for iteration 0: 32 consecutive row-indices, lanes 32-63 mirror 0-31
        int iv = y_true[wid * 32 + (lane & 31)];
        for (int t = 0; t < F; ++t) {
            const int rb = (t * NW + wid) * 32;   // first row of this wave's 32-row tile

            // extract per-quad idx (reg-resident iv -> ds_bpermute) and issue
            // exec-masked loads back-to-back: 8 independent chains, line elision kept
            float4 v0 = {0,0,0,0}, v1 = {0,0,0,0}, v2 = {0,0,0,0}, v3 = {0,0,0,0};
            float4 v4 = {0,0,0,0}, v5 = {0,0,0,0}, v6 = {0,0,0,0}, v7 = {0,0,0,0};
            const int i0 = __shfl(iv,  0 + sub, 64);
            if (i0 ? (b4 + 3 >= i0) : (c == 0)) v0 = *(const float4*)(y_pred + (rb +  0 + sub) * 64 + b4);
            const int i1 = __shfl(iv,  4 + sub, 64);
            if (i1 ? (b4 + 3 >= i1) : (c == 0)) v1 = *(const float4*)(y_pred + (rb +  4 + sub) * 64 + b4);
            const int i2 = __shfl(iv,  8 + sub, 64);
            if (i2 ? (b4 + 3 >= i2) : (c == 0)) v2 = *(const float4*)(y_pred + (rb +  8 + sub) * 64 + b4);
            const int i3 = __shfl(iv, 12 + sub, 64);
            if (i3 ? (b4 + 3 >= i3) : (c == 0)) v3 = *(const float4*)(y_pred + (rb + 12 + sub) * 64 + b4);
            const int i4 = __shfl(iv, 16 + sub, 64);
            if (i4 ? (b4 + 3 >= i4) : (c == 0)) v4 = *(const float4*)(y_pred + (rb + 16 + sub) * 64 + b4);
            const int i5 = __shfl(iv, 20 + sub, 64);
            if (i5 ? (b4 + 3 >= i5) : (c == 0)) v5 = *(const float4*)(y_pred + (rb + 20 + sub) * 64 + b4);
            const int i6 = __shfl(iv, 24 + sub, 64);
            if (i6 ? (b4 + 3 >= i6) : (c == 0)) v6 = *(const float4*)(y_pred + (rb + 24 + sub) * 64 + b4);
            const int i7 = __shfl(iv, 28 + sub, 64);
            if (i7 ? (b4 + 3 >= i7) : (c == 0)) v7 = *(const float4*)(y_pred + (rb + 28 + sub) * 64 + b4);

            // prefetch next iteration's idx vector under the loads above
            int ivn = 0;
            if (t + 1 < F) ivn = y_true[(t + 1) * NW * 32 + wid * 32 + (lane & 31)];

            const float s0 = reduce16(masked_val(v0, i0, b4, c));
            const float s1 = reduce16(masked_val(v1, i1, b4, c));
            const float s2 = reduce16(masked_val(v2, i2, b4, c));
            const float s3 = reduce16(masked_val(v3, i3, b4, c));
            const float s4 = reduce16(masked_val(v4, i4, b4, c));
            const float s5 = reduce16(masked_val(v5, i5, b4, c));
            const float s6 = reduce16(masked_val(v6, i6, b4, c));
            const float s7 = reduce16(masked_val(v7, i7, b4, c));

            if (c == 0) {
                local += nll_term(s0, i0, w) + nll_term(s1, i1, w)
                       + nll_term(s2, i2, w) + nll_term(s3, i3, w);
                local += nll_term(s4, i4, w) + nll_term(s5, i5, w)
                       + nll_term(s6, i6, w) + nll_term(s7, i7, w);
            }
            iv = ivn;
        }
    }

    // tail: per-quad with validity (empty for B = 2^21)
    for (int q = F * NW * 8 + wid; q < nquads; q += NW) {
        const int r = q * 4 + sub;
        const bool valid = r < B;
        int idx = 0;
        if (valid) idx = y_true[r];
        float4 v = {0,0,0,0};
        if (valid && (idx ? (b4 + 3 >= idx) : (c == 0)))
            v = *(const float4*)(y_pred + r * 64 + b4);
        const float s = reduce16(masked_val(v, idx, b4, c));
        if (c == 0 && valid) local += nll_term(s, idx, w);
    }

    // wave sum -> block sum -> device accumulator; last block finalizes
    #pragma unroll
    for (int off = 32; off; off >>= 1) local += __shfl_xor(local, off, 64);
    __shared__ float bred[TPB / 64];
    if (lane == 0) bred[wv] = local;
    __syncthreads();
    if (threadIdx.x == 0) {
        atomicAdd(acc, (double)(bred[0] + bred[1] + bred[2] + bred[3]));
        __threadfence();
        const int old = atomicAdd(ticket, 1);
        if (old == NBLK - 1) {
            const double total = atomicAdd(acc, 0.0);   // coherent read-back
            out[0] = (float)(total / (double)B);
        }
    }
}

extern "C" void kernel_launch(void* const* d_in, const int* in_sizes, int n_in,
                              void* d_out, int out_size, void* d_ws, size_t ws_size,
                              hipStream_t stream) {
    const float* y_pred = (const float*)d_in[0];
    const int*   y_true = (const int*)d_in[1];
    const float* w      = (const float*)d_in[2];
    float* out    = (float*)d_out;
    double* acc   = (double*)d_ws;
    int*   ticket = (int*)((char*)d_ws + 8);

    const int B = in_sizes[1];   // rows (y_true has B elements)

    (void)hipMemsetAsync(d_ws, 0, 16, stream);
    CLL_main<<<NBLK, TPB, 0, stream>>>(y_pred, y_true, w, acc, ticket, out, B);
}

// Round 8
// 154.204 us; speedup vs baseline: 1.1940x; 1.1940x over previous
//
#include <hip/hip_runtime.h>

#define TPB 256
#define NBLK 2048
#define NW (NBLK * TPB / 64)   // 8192 waves

template <int CTRL>
__device__ __forceinline__ float dpp_add(float v) {
    int x = __builtin_amdgcn_update_dpp(0, __float_as_int(v), CTRL, 0xf, 0xf, true);
    return v + __int_as_float(x);
}

__device__ __forceinline__ float reduce16(float s) {
    s = dpp_add<0xB1>(s);    // quad_perm xor1
    s = dpp_add<0x4E>(s);    // quad_perm xor2
    s = dpp_add<0x124>(s);   // row_ror:4
    s = dpp_add<0x128>(s);   // row_ror:8
    return s;
}

__device__ __forceinline__ float masked_val(float4 v, int idx, int b4, int c) {
    float ms = (b4     >= idx ? v.x : 0.f)
             + (b4 + 1 >= idx ? v.y : 0.f)
             + (b4 + 2 >= idx ? v.z : 0.f)
             + (b4 + 3 >= idx ? v.w : 0.f);
    return idx ? ms : ((c == 0) ? v.x : 0.f);
}

__device__ __forceinline__ float nll_term(float s, int i, const float* __restrict__ w) {
    return -__logf(fminf(fmaxf(s, 1e-15f), 1.0f)) * w[i];
}

__global__ __launch_bounds__(TPB, 8) void CLL_main(
    const float* __restrict__ y_pred,
    const int*   __restrict__ y_true,
    const float* __restrict__ w,
    double*      __restrict__ acc,
    int*         __restrict__ ticket,
    float*       __restrict__ out,
    const int B)
{
    const int lane = threadIdx.x & 63;
    const int wv   = threadIdx.x >> 6;   // wave within block (0..3)
    const int c    = lane & 15;          // chunk within row (4 floats)
    const int sub  = lane >> 4;          // row within quad
    const int b4   = c << 2;
    const int wid  = (blockIdx.x * TPB + threadIdx.x) >> 6;
    const int nw   = NW;
    const int nquads = (B + 3) >> 2;

    float local = 0.0f;
    int qi = wid;

    if (qi + 3 * nw < nquads) {
        // prologue: idx for first iteration (4 loads, 16-lanes-same-address each)
        int i0 = y_true[(qi         ) * 4 + sub];
        int i1 = y_true[(qi +     nw) * 4 + sub];
        int i2 = y_true[(qi + 2 * nw) * 4 + sub];
        int i3 = y_true[(qi + 3 * nw) * 4 + sub];
        for (;;) {
            const int r0 = (qi         ) * 4 + sub;
            const int r1 = (qi +     nw) * 4 + sub;
            const int r2 = (qi + 2 * nw) * 4 + sub;
            const int r3 = (qi + 3 * nw) * 4 + sub;

            // 4 independent exec-masked float4 loads — line elision preserved,
            // predicates depend only on reg-resident idx (no LDS in the path)
            float4 v0 = {0,0,0,0}, v1 = {0,0,0,0}, v2 = {0,0,0,0}, v3 = {0,0,0,0};
            if (i0 ? (b4 + 3 >= i0) : (c == 0)) v0 = *(const float4*)(y_pred + r0 * 64 + b4);
            if (i1 ? (b4 + 3 >= i1) : (c == 0)) v1 = *(const float4*)(y_pred + r1 * 64 + b4);
            if (i2 ? (b4 + 3 >= i2) : (c == 0)) v2 = *(const float4*)(y_pred + r2 * 64 + b4);
            if (i3 ? (b4 + 3 >= i3) : (c == 0)) v3 = *(const float4*)(y_pred + r3 * 64 + b4);

            // prefetch next iteration's idx under the loads above
            const int qn = qi + 4 * nw;
            const bool more = (qn + 3 * nw < nquads);   // wave-uniform
            int n0 = 0, n1 = 0, n2 = 0, n3 = 0;
            if (more) {
                n0 = y_true[(qn         ) * 4 + sub];
                n1 = y_true[(qn +     nw) * 4 + sub];
                n2 = y_true[(qn + 2 * nw) * 4 + sub];
                n3 = y_true[(qn + 3 * nw) * 4 + sub];
            }

            const float s0 = reduce16(masked_val(v0, i0, b4, c));
            const float s1 = reduce16(masked_val(v1, i1, b4, c));
            const float s2 = reduce16(masked_val(v2, i2, b4, c));
            const float s3 = reduce16(masked_val(v3, i3, b4, c));

            if (c == 0) {
                local += nll_term(s0, i0, w);
                local += nll_term(s1, i1, w);
                local += nll_term(s2, i2, w);
                local += nll_term(s3, i3, w);
            }

            qi = qn;
            if (!more) break;
            i0 = n0; i1 = n1; i2 = n2; i3 = n3;
        }
    }

    // tail: one quad at a time with validity (not taken for B = 2^21)
    for (; qi < nquads; qi += nw) {
        const int r = qi * 4 + sub;
        const bool valid = r < B;
        int idx = 0;
        if (valid) idx = y_true[r];
        float4 v = {0,0,0,0};
        if (valid && (idx ? (b4 + 3 >= idx) : (c == 0)))
            v = *(const float4*)(y_pred + r * 64 + b4);
        const float s = reduce16(masked_val(v, idx, b4, c));
        if (c == 0 && valid) local += nll_term(s, idx, w);
    }

    // wave sum -> block sum -> device accumulator; last block finalizes
    #pragma unroll
    for (int off = 32; off; off >>= 1) local += __shfl_xor(local, off, 64);
    __shared__ float bred[TPB / 64];
    if (lane == 0) bred[wv] = local;
    __syncthreads();
    if (threadIdx.x == 0) {
        atomicAdd(acc, (double)(bred[0] + bred[1] + bred[2] + bred[3]));
        __threadfence();
        const int old = atomicAdd(ticket, 1);
        if (old == NBLK - 1) {
            const double total = atomicAdd(acc, 0.0);   // device-coherent read-back
            out[0] = (float)(total / (double)B);
        }
    }
}

extern "C" void kernel_launch(void* const* d_in, const int* in_sizes, int n_in,
                              void* d_out, int out_size, void* d_ws, size_t ws_size,
                              hipStream_t stream) {
    const float* y_pred = (const float*)d_in[0];
    const int*   y_true = (const int*)d_in[1];
    const float* w      = (const float*)d_in[2];
    float* out    = (float*)d_out;
    double* acc   = (double*)d_ws;
    int*   ticket = (int*)((char*)d_ws + 8);

    const int B = in_sizes[1];   // rows (y_true has B elements)

    (void)hipMemsetAsync(d_ws, 0, 16, stream);
    CLL_main<<<NBLK, TPB, 0, stream>>>(y_pred, y_true, w, acc, ticket, out, B);
}

// Round 9
// 73.804 us; speedup vs baseline: 2.4948x; 2.0894x over previous
//
#include <hip/hip_runtime.h>

#define TPB 256
#define NBLK 2048
#define NW (NBLK * TPB / 64)   // 8192 waves

template <int CTRL>
__device__ __forceinline__ float dpp_add(float v) {
    int x = __builtin_amdgcn_update_dpp(0, __float_as_int(v), CTRL, 0xf, 0xf, true);
    return v + __int_as_float(x);
}

__device__ __forceinline__ float reduce16(float s) {
    s = dpp_add<0xB1>(s);    // quad_perm xor1
    s = dpp_add<0x4E>(s);    // quad_perm xor2
    s = dpp_add<0x124>(s);   // row_ror:4
    s = dpp_add<0x128>(s);   // row_ror:8
    return s;
}

__device__ __forceinline__ float masked_val(float4 v, int idx, int b4, int c) {
    float ms = (b4     >= idx ? v.x : 0.f)
             + (b4 + 1 >= idx ? v.y : 0.f)
             + (b4 + 2 >= idx ? v.z : 0.f)
             + (b4 + 3 >= idx ? v.w : 0.f);
    return idx ? ms : ((c == 0) ? v.x : 0.f);
}

__device__ __forceinline__ float nll_term(float s, int i, const float* __restrict__ w) {
    return -__logf(fminf(fmaxf(s, 1e-15f), 1.0f)) * w[i];
}

__global__ __launch_bounds__(TPB, 8) void CLL_main(
    const float* __restrict__ y_pred,
    const int*   __restrict__ y_true,
    const float* __restrict__ w,
    float*       __restrict__ partial,
    const int B)
{
    const int lane = threadIdx.x & 63;
    const int wv   = threadIdx.x >> 6;   // wave within block (0..3)
    const int c    = lane & 15;          // chunk within row (4 floats)
    const int sub  = lane >> 4;          // row within quad
    const int b4   = c << 2;
    const int wid  = (blockIdx.x * TPB + threadIdx.x) >> 6;
    const int nquads = (B + 3) >> 2;
    const int ntiles = B >> 4;           // full 16-row tiles (2^17 for B=2^21)

    float local = 0.0f;

    // main loop: each wave owns 16 CONSECUTIVE rows per iteration -> its 4-load
    // burst covers one contiguous 4KB window; idx loads hit one 64B region.
    int ti = wid;
    if (ti < ntiles) {
        int i0 = y_true[ti * 16 +  0 + sub];
        int i1 = y_true[ti * 16 +  4 + sub];
        int i2 = y_true[ti * 16 +  8 + sub];
        int i3 = y_true[ti * 16 + 12 + sub];
        for (;;) {
            const float* rp = y_pred + (ti * 16 + sub) * 64 + b4;

            // 4 independent exec-masked float4 loads, offsets 0/1024/2048/3072 B
            float4 v0 = {0,0,0,0}, v1 = {0,0,0,0}, v2 = {0,0,0,0}, v3 = {0,0,0,0};
            if (i0 ? (b4 + 3 >= i0) : (c == 0)) v0 = *(const float4*)(rp        );
            if (i1 ? (b4 + 3 >= i1) : (c == 0)) v1 = *(const float4*)(rp +  256);
            if (i2 ? (b4 + 3 >= i2) : (c == 0)) v2 = *(const float4*)(rp +  512);
            if (i3 ? (b4 + 3 >= i3) : (c == 0)) v3 = *(const float4*)(rp +  768);

            // prefetch next tile's idx under the loads above
            const int tn = ti + NW;
            const bool more = tn < ntiles;   // wave-uniform
            int n0 = 0, n1 = 0, n2 = 0, n3 = 0;
            if (more) {
                n0 = y_true[tn * 16 +  0 + sub];
                n1 = y_true[tn * 16 +  4 + sub];
                n2 = y_true[tn * 16 +  8 + sub];
                n3 = y_true[tn * 16 + 12 + sub];
            }

            const float s0 = reduce16(masked_val(v0, i0, b4, c));
            const float s1 = reduce16(masked_val(v1, i1, b4, c));
            const float s2 = reduce16(masked_val(v2, i2, b4, c));
            const float s3 = reduce16(masked_val(v3, i3, b4, c));

            if (c == 0) {
                local += nll_term(s0, i0, w);
                local += nll_term(s1, i1, w);
                local += nll_term(s2, i2, w);
                local += nll_term(s3, i3, w);
            }

            ti = tn;
            if (!more) break;
            i0 = n0; i1 = n1; i2 = n2; i3 = n3;
        }
    }

    // tail: rows past ntiles*16, per-quad with validity (empty for B = 2^21)
    for (int q = ntiles * 4 + wid; q < nquads; q += NW) {
        const int r = q * 4 + sub;
        const bool valid = r < B;
        int idx = 0;
        if (valid) idx = y_true[r];
        float4 v = {0,0,0,0};
        if (valid && (idx ? (b4 + 3 >= idx) : (c == 0)))
            v = *(const float4*)(y_pred + r * 64 + b4);
        const float s = reduce16(masked_val(v, idx, b4, c));
        if (c == 0 && valid) local += nll_term(s, idx, w);
    }

    // wave sum, then block sum via LDS -> one partial per block
    #pragma unroll
    for (int off = 32; off; off >>= 1) local += __shfl_xor(local, off, 64);
    __shared__ float bred[TPB / 64];
    if (lane == 0) bred[wv] = local;
    __syncthreads();
    if (threadIdx.x == 0)
        partial[blockIdx.x] = bred[0] + bred[1] + bred[2] + bred[3];
}

__global__ __launch_bounds__(1024) void CLL_final(
    const float* __restrict__ partial, float* __restrict__ out, const int B)
{
    __shared__ double red[16];
    double s = 0.0;
    for (int i = threadIdx.x; i < NBLK; i += 1024) s += (double)partial[i];
    #pragma unroll
    for (int off = 32; off; off >>= 1) s += __shfl_xor(s, off, 64);
    if ((threadIdx.x & 63) == 0) red[threadIdx.x >> 6] = s;
    __syncthreads();
    if (threadIdx.x == 0) {
        double t = 0.0;
        #pragma unroll
        for (int i = 0; i < 16; ++i) t += red[i];
        out[0] = (float)(t / (double)B);
    }
}

extern "C" void kernel_launch(void* const* d_in, const int* in_sizes, int n_in,
                              void* d_out, int out_size, void* d_ws, size_t ws_size,
                              hipStream_t stream) {
    const float* y_pred = (const float*)d_in[0];
    const int*   y_true = (const int*)d_in[1];
    const float* w      = (const float*)d_in[2];
    float* out  = (float*)d_out;
    float* part = (float*)d_ws;

    const int B = in_sizes[1];   // rows (y_true has B elements)

    CLL_main<<<NBLK, TPB, 0, stream>>>(y_pred, y_true, w, part, B);
    CLL_final<<<1, 1024, 0, stream>>>(part, out, B);
}